// Round 1
// baseline (24006.677 us; speedup 1.0000x reference)
//
#include <hip/hip_runtime.h>
#include <math.h>

#define HD 512   // hidden size H
#define TT 512   // sequence length T
#define NB 128   // batch B
#define G3 1536  // 3*H

// Tiled transpose: A (rows x cols) -> At (cols x rows)
__global__ __launch_bounds__(256) void transpose_tiled(const float* __restrict__ A,
                                                       float* __restrict__ At,
                                                       int rows, int cols) {
    __shared__ float tile[32][33];
    int bx = blockIdx.x * 32;  // col base in A
    int by = blockIdx.y * 32;  // row base in A
    int tx = threadIdx.x, ty = threadIdx.y;  // 32 x 8
    #pragma unroll
    for (int i = 0; i < 32; i += 8)
        tile[ty + i][tx] = A[(by + ty + i) * cols + (bx + tx)];
    __syncthreads();
    #pragma unroll
    for (int i = 0; i < 32; i += 8)
        At[(bx + ty + i) * rows + (by + tx)] = tile[tx][ty + i];
}

__device__ __forceinline__ float sigm(float v) {
    return 1.0f / (1.0f + __expf(-v));
}

// One block per batch element; thread t owns hidden unit t.
// WhT layout: WhT[k*1536 + j] = Wh[j*512 + k]  (k = input unit, j = output row)
__global__ __launch_bounds__(512) void gru_ae(
    const float* __restrict__ x,
    const float* __restrict__ eWi, const float* __restrict__ ebi, const float* __restrict__ ebh,
    const float* __restrict__ dWi, const float* __restrict__ dbi, const float* __restrict__ dbh,
    const float* __restrict__ linW, const float* __restrict__ linb,
    const float* __restrict__ eWhT, const float* __restrict__ dWhT,
    float* __restrict__ out)
{
    const int b = blockIdx.x;
    const int t = threadIdx.x;  // 0..511

    __shared__ float h_s[HD];
    __shared__ float red_s[8];
    __shared__ float y_sh;

    h_s[t] = 0.0f;
    const float lw = linW[t];
    const float lb = linb[0];

    // encoder per-thread params
    float wi_r = eWi[t], wi_z = eWi[HD + t], wi_n = eWi[2 * HD + t];
    float c_r  = ebi[t] + ebh[t];
    float c_z  = ebi[HD + t] + ebh[HD + t];
    float bi_n = ebi[2 * HD + t], bh_n = ebh[2 * HD + t];
    __syncthreads();

    // ---------------- encoder ----------------
    {
        const float* wp = eWhT + t;
        for (int step = 0; step < TT; ++step) {
            float xt = x[b * TT + step];
            float ar = 0.f, az = 0.f, an = 0.f;
            #pragma unroll 8
            for (int k = 0; k < HD; ++k) {
                float hk = h_s[k];
                ar = fmaf(wp[k * G3           ], hk, ar);
                az = fmaf(wp[k * G3 +      HD ], hk, az);
                an = fmaf(wp[k * G3 + 2 * HD ], hk, an);
            }
            float r  = sigm(fmaf(xt, wi_r, c_r) + ar);
            float z  = sigm(fmaf(xt, wi_z, c_z) + az);
            float n  = tanhf(fmaf(xt, wi_n, bi_n) + r * (an + bh_n));
            float hn = fmaf(z, h_s[t] - n, n);  // (1-z)*n + z*h
            __syncthreads();
            h_s[t] = hn;
            __syncthreads();
        }
    }

    // switch to decoder params
    wi_r = dWi[t]; wi_z = dWi[HD + t]; wi_n = dWi[2 * HD + t];
    c_r  = dbi[t] + dbh[t];
    c_z  = dbi[HD + t] + dbh[HD + t];
    bi_n = dbi[2 * HD + t]; bh_n = dbh[2 * HD + t];

    // y = h @ linW^T + lb   (block-wide dot)
    float y;
    {
        float p = h_s[t] * lw;
        #pragma unroll
        for (int o = 32; o >= 1; o >>= 1) p += __shfl_down(p, o);
        if ((t & 63) == 0) red_s[t >> 6] = p;
        __syncthreads();
        if (t == 0) {
            float s = lb;
            #pragma unroll
            for (int i = 0; i < 8; ++i) s += red_s[i];
            y_sh = s;
        }
        __syncthreads();
        y = y_sh;
    }

    // ---------------- decoder ----------------
    {
        const float* wp = dWhT + t;
        for (int step = 0; step < TT; ++step) {
            float ar = 0.f, az = 0.f, an = 0.f;
            #pragma unroll 8
            for (int k = 0; k < HD; ++k) {
                float hk = h_s[k];
                ar = fmaf(wp[k * G3           ], hk, ar);
                az = fmaf(wp[k * G3 +      HD ], hk, az);
                an = fmaf(wp[k * G3 + 2 * HD ], hk, an);
            }
            float r  = sigm(fmaf(y, wi_r, c_r) + ar);
            float z  = sigm(fmaf(y, wi_z, c_z) + az);
            float n  = tanhf(fmaf(y, wi_n, bi_n) + r * (an + bh_n));
            float hn = fmaf(z, h_s[t] - n, n);
            __syncthreads();
            h_s[t] = hn;
            __syncthreads();

            // y = h @ linW^T + lb ; emit flipped
            float p = hn * lw;
            #pragma unroll
            for (int o = 32; o >= 1; o >>= 1) p += __shfl_down(p, o);
            if ((t & 63) == 0) red_s[t >> 6] = p;
            __syncthreads();
            if (t == 0) {
                float s = lb;
                #pragma unroll
                for (int i = 0; i < 8; ++i) s += red_s[i];
                y_sh = s;
                out[b * TT + (TT - 1 - step)] = s;
            }
            __syncthreads();
            y = y_sh;
        }
    }
}

extern "C" void kernel_launch(void* const* d_in, const int* in_sizes, int n_in,
                              void* d_out, int out_size, void* d_ws, size_t ws_size,
                              hipStream_t stream) {
    const float* x    = (const float*)d_in[0];
    const float* eWi  = (const float*)d_in[1];
    const float* eWh  = (const float*)d_in[2];
    const float* ebi  = (const float*)d_in[3];
    const float* ebh  = (const float*)d_in[4];
    const float* dWi  = (const float*)d_in[5];
    const float* dWh  = (const float*)d_in[6];
    const float* dbi  = (const float*)d_in[7];
    const float* dbh  = (const float*)d_in[8];
    const float* linW = (const float*)d_in[9];
    const float* linb = (const float*)d_in[10];
    float* out  = (float*)d_out;

    float* eWhT = (float*)d_ws;            // 512 x 1536 fp32 = 3 MB
    float* dWhT = eWhT + (size_t)G3 * HD;  // 3 MB

    dim3 tb(32, 8), tg(HD / 32, G3 / 32);
    transpose_tiled<<<tg, tb, 0, stream>>>(eWh, eWhT, G3, HD);
    transpose_tiled<<<tg, tb, 0, stream>>>(dWh, dWhT, G3, HD);

    gru_ae<<<dim3(NB), dim3(HD), 0, stream>>>(x, eWi, ebi, ebh, dWi, dbi, dbh,
                                              linW, linb, eWhT, dWhT, out);
}